// Round 2
// baseline (892.749 us; speedup 1.0000x reference)
//
#include <hip/hip_runtime.h>
#include <hip/hip_bf16.h>
#include <cstdint>
#include <cstddef>

#define D_MODEL 1024
#define FF_DIM  4096
#define NEXP    8
#define TOK     8192
#define CAP     2560          // ceil(1.25 * 8192*2 / 8)
#define ECAP    (NEXP*CAP)    // 20480
#define LSCALE  2.0f          // lora_alpha / rank = 4/2

typedef __attribute__((ext_vector_type(8))) short  short8;
typedef __attribute__((ext_vector_type(4))) float  f32x4;

__device__ __forceinline__ unsigned short f2bf(float f){
  unsigned int u = __float_as_uint(f);
  u += 0x7fffu + ((u >> 16) & 1u);
  return (unsigned short)(u >> 16);
}
__device__ __forceinline__ float bf2f(unsigned short s){
  return __uint_as_float(((unsigned int)s) << 16);
}
__device__ __forceinline__ void gload16(const void* g, void* l){
  __builtin_amdgcn_global_load_lds((const __attribute__((address_space(1))) void*)g,
                                   (__attribute__((address_space(3))) void*)l, 16, 0, 0);
}
__device__ __forceinline__ float gelu_tanh(float x){
  // jax.nn.gelu approximate=True
  float u = 0.7978845608028654f * (x + 0.044715f * x * x * x);
  float e = __expf(2.0f * u);
  float t = 1.0f - 2.0f / (e + 1.0f);
  return 0.5f * x * (1.0f + t);
}

// ------------- transpose W1 [D][FF] -> W1bf [FF][D] (bf16) -------------------
__global__ void tr_w1(const float* __restrict__ W1, unsigned short* __restrict__ W1bf)
{
  __shared__ float tile[64][65];          // tile[d_local][f_local]
  int d0 = blockIdx.x * 64;               // 16 blocks
  int f0 = blockIdx.y * 64;               // 64 blocks
  int tid = threadIdx.x;
  int r  = tid >> 4;                      // 0..15
  int c4 = (tid & 15) * 4;                // 0..60
#pragma unroll
  for (int i = 0; i < 4; i++){
    int dl = r + i*16;
    float4 v = *(const float4*)(W1 + (size_t)(d0 + dl) * FF_DIM + f0 + c4);
    tile[dl][c4+0] = v.x; tile[dl][c4+1] = v.y; tile[dl][c4+2] = v.z; tile[dl][c4+3] = v.w;
  }
  __syncthreads();
#pragma unroll
  for (int i = 0; i < 4; i++){
    int fl = r + i*16;
    int f  = f0 + fl;
    ushort4 o;
    o.x = f2bf(tile[c4+0][fl]);
    o.y = f2bf(tile[c4+1][fl]);
    o.z = f2bf(tile[c4+2][fl]);
    o.w = f2bf(tile[c4+3][fl]);
    *(ushort4*)(W1bf + (size_t)f * D_MODEL + d0 + c4) = o;
  }
}

// ------------- transpose W2 [FF][D] -> W2bf [D][FF] (bf16) -------------------
__global__ void tr_w2(const float* __restrict__ W2, unsigned short* __restrict__ W2bf)
{
  __shared__ float tile[64][65];          // tile[f_local][d_local]
  int d0 = blockIdx.x * 64;               // 16 blocks
  int f0 = blockIdx.y * 64;               // 64 blocks
  int tid = threadIdx.x;
  int r  = tid >> 4;
  int c4 = (tid & 15) * 4;
#pragma unroll
  for (int i = 0; i < 4; i++){
    int fl = r + i*16;
    float4 v = *(const float4*)(W2 + (size_t)(f0 + fl) * D_MODEL + d0 + c4);
    tile[fl][c4+0] = v.x; tile[fl][c4+1] = v.y; tile[fl][c4+2] = v.z; tile[fl][c4+3] = v.w;
  }
  __syncthreads();
#pragma unroll
  for (int i = 0; i < 4; i++){
    int dl = r + i*16;
    int d  = d0 + dl;
    ushort4 o;
    o.x = f2bf(tile[c4+0][dl]);
    o.y = f2bf(tile[c4+1][dl]);
    o.z = f2bf(tile[c4+2][dl]);
    o.w = f2bf(tile[c4+3][dl]);
    *(ushort4*)(W2bf + (size_t)d * FF_DIM + f0 + c4) = o;
  }
}

// ---------------- gating: one wave per token --------------------------------
__global__ void gate_kernel(const float* __restrict__ x, const float* __restrict__ Wg,
                            int* __restrict__ exp_flat, float* __restrict__ g_flat)
{
  int lane = threadIdx.x & 63;
  int wave = threadIdx.x >> 6;
  int t = blockIdx.x * 4 + wave;
  const float4* xv = (const float4*)(x + (size_t)t * D_MODEL);
  float acc[8];
#pragma unroll
  for (int e = 0; e < 8; e++) acc[e] = 0.f;
#pragma unroll
  for (int i = 0; i < 4; i++){
    int i4 = lane + i*64;
    float4 v = xv[i4];
#pragma unroll
    for (int k = 0; k < 4; k++){
      float xs = (&v.x)[k];
      const float4* wr = (const float4*)(Wg + (size_t)(i4*4 + k) * 8);
      float4 w0 = wr[0], w1 = wr[1];
      acc[0] += xs*w0.x; acc[1] += xs*w0.y; acc[2] += xs*w0.z; acc[3] += xs*w0.w;
      acc[4] += xs*w1.x; acc[5] += xs*w1.y; acc[6] += xs*w1.z; acc[7] += xs*w1.w;
    }
  }
#pragma unroll
  for (int off = 32; off > 0; off >>= 1){
#pragma unroll
    for (int e = 0; e < 8; e++) acc[e] += __shfl_down(acc[e], off);
  }
  if (lane == 0){
    float m0 = acc[0]; int e0 = 0;
#pragma unroll
    for (int e = 1; e < 8; e++) if (acc[e] > m0){ m0 = acc[e]; e0 = e; }
    float m1 = -3.4e38f; int e1 = 0;
#pragma unroll
    for (int e = 0; e < 8; e++) if (e != e0 && acc[e] > m1){ m1 = acc[e]; e1 = e; }
    float z = __expf(m1 - m0);
    float inv = 1.f / (1.f + z);
    exp_flat[t]       = e0;
    exp_flat[TOK + t] = e1;
    g_flat[t]         = inv;
    g_flat[TOK + t]   = z * inv;
  }
}

// ---------------- routing: exact slot-major cumulative positions -------------
__global__ void route_kernel(const int* __restrict__ exp_flat, const float* __restrict__ g_flat,
                             int* __restrict__ slotidx, float* __restrict__ wcomb,
                             int* __restrict__ fillc)
{
  int lane = threadIdx.x;  // 64 threads, single wave
  unsigned long long ltmask = (1ull << lane) - 1ull;
  int cnt[8];
#pragma unroll
  for (int q = 0; q < 8; q++) cnt[q] = 0;
  for (int j0 = 0; j0 < 2*TOK; j0 += 64){
    int   e = exp_flat[j0 + lane];
    float g = g_flat[j0 + lane];
    int pos = 0;
#pragma unroll
    for (int q = 0; q < 8; q++){
      unsigned long long m = __ballot(e == q);
      if (e == q) pos = cnt[q] + __popcll(m & ltmask);
      cnt[q] += __popcll(m);
    }
    bool keep = pos < CAP;
    slotidx[j0 + lane] = e*CAP + (keep ? pos : (CAP-1));
    wcomb[j0 + lane]   = keep ? g : 0.f;
  }
  if (lane < 8) fillc[lane] = cnt[lane] < CAP ? cnt[lane] : CAP;
}

// ---------------- init: zero pooled + wslot ----------------------------------
__global__ void init_zero(float* __restrict__ pooled, float* __restrict__ wslot)
{
  int i = blockIdx.x * 256 + threadIdx.x;   // grid 96 -> 24576 = 4096 + 20480
  if (i < 4*D_MODEL) pooled[i] = 0.f;
  else wslot[i - 4*D_MODEL] = 0.f;
}

// ---------------- dispatch: scatter tokens into capacity buffer (bf16) -------
__global__ void dispatch_kernel(const float* __restrict__ x, const int* __restrict__ slotidx,
                                const float* __restrict__ wcomb, unsigned short* __restrict__ dispA,
                                float* __restrict__ wslot, int* __restrict__ tbat)
{
  int j = blockIdx.x;
  float w = wcomb[j];
  if (w == 0.f) return;                 // dropped (uniform branch)
  int t = j & (TOK - 1);
  int slot = slotidx[j];
  int i = threadIdx.x;                  // 128 threads, 8 elems each
  const float4* src = (const float4*)(x + (size_t)t * D_MODEL);
  float4 a = src[2*i], b = src[2*i+1];
  ushort4 o0, o1;
  o0.x = f2bf(a.x); o0.y = f2bf(a.y); o0.z = f2bf(a.z); o0.w = f2bf(a.w);
  o1.x = f2bf(b.x); o1.y = f2bf(b.y); o1.z = f2bf(b.z); o1.w = f2bf(b.w);
  ushort4* dst = (ushort4*)(dispA + (size_t)slot * D_MODEL + i*8);
  dst[0] = o0; dst[1] = o1;
  if (i == 0){ wslot[slot] = w; tbat[slot] = t >> 11; }
}

// ---------------- LoRA rank-2 projection: U[slot][r] = X_row . A_e[:,r] ------
__global__ void lora_u(const unsigned short* __restrict__ X, const float* __restrict__ Aw,
                       float* __restrict__ U, int Kdim)
{
  int lane = threadIdx.x & 63;
  int wv   = threadIdx.x >> 6;
  int slot = blockIdx.x * 4 + wv;       // 5120 blocks -> 20480 slots
  int e = slot / CAP;
  const ushort4* row = (const ushort4*)(X + (size_t)slot * Kdim);
  const float2*  Av  = (const float2*)(Aw + (size_t)e * Kdim * 2);  // Av[d] = (r0, r1)
  float a0 = 0.f, a1 = 0.f;
  int n4 = Kdim >> 2;
  for (int i4 = lane; i4 < n4; i4 += 64){
    ushort4 v = row[i4];
    int d = i4 * 4;
    float2 w0 = Av[d], w1 = Av[d+1], w2 = Av[d+2], w3 = Av[d+3];
    float x0 = bf2f(v.x), x1 = bf2f(v.y), x2 = bf2f(v.z), x3 = bf2f(v.w);
    a0 += x0*w0.x + x1*w1.x + x2*w2.x + x3*w3.x;
    a1 += x0*w0.y + x1*w1.y + x2*w2.y + x3*w3.y;
  }
#pragma unroll
  for (int off = 32; off > 0; off >>= 1){
    a0 += __shfl_down(a0, off);
    a1 += __shfl_down(a1, off);
  }
  if (lane == 0){ U[slot*2] = a0; U[slot*2+1] = a1; }
}

// ---------------- m97-style bf16 GEMM, C = A * Bt^T + LoRA correction --------
// A [20480, K] row-major, Bt [N, K] row-major (shared across experts),
// U [20480][2] f32 LoRA projections, Bl [E][2][N] f32 LoRA B-matrix.
// GELU: apply gelu, write bf16 C.  COMBINE: no C write; pooled += w*val.
template<bool GELU, bool COMBINE>
__global__ __launch_bounds__(256) void gemm_bt(const unsigned short* __restrict__ A,
                                               const unsigned short* __restrict__ Bt,
                                               unsigned short* __restrict__ Cb,
                                               int K, int N, const int* __restrict__ fillc,
                                               const float* __restrict__ U,
                                               const float* __restrict__ Bl,
                                               const float* __restrict__ wslot,
                                               const int* __restrict__ tbat,
                                               float* __restrict__ pooled)
{
  int e = blockIdx.x / 20;                       // CAP/128 = 20 row tiles per expert
  int rowInExp = (blockIdx.x % 20) * 128;
  if (rowInExp >= fillc[e]) return;              // skip tiles with no kept tokens
  int row0 = blockIdx.x * 128;
  int col0 = blockIdx.y * 128;

  __shared__ __align__(16) unsigned short As[128*32];
  __shared__ __align__(16) unsigned short Bs[128*32];
  __shared__ float part[512];                    // [4 batches][128 cols] for COMBINE

  int tid  = threadIdx.x;
  int lane = tid & 63;
  int wave = tid >> 6;
  int wm = wave & 1, wn = wave >> 1;

  if (COMBINE){ part[tid] = 0.f; part[tid + 256] = 0.f; }

  const unsigned short* gA = A  + (size_t)(row0 + wave*32 + (lane>>2)) * K + ((lane&3)*8);
  const unsigned short* gB = Bt + (size_t)(col0 + wave*32 + (lane>>2)) * K + ((lane&3)*8);
  unsigned short* lA = As + wave*1024;           // wave-uniform LDS base
  unsigned short* lB = Bs + wave*1024;

  f32x4 acc[4][4];
#pragma unroll
  for (int i = 0; i < 4; i++)
#pragma unroll
    for (int j = 0; j < 4; j++)
      acc[i][j] = (f32x4){0.f, 0.f, 0.f, 0.f};

  int rb = lane & 15;
  int q  = lane >> 4;

  for (int k0 = 0; k0 < K; k0 += 32){
    __syncthreads();
    gload16(gA + k0,          lA);
    gload16(gA + k0 + 16*K,   lA + 512);
    gload16(gB + k0,          lB);
    gload16(gB + k0 + 16*K,   lB + 512);
    __syncthreads();
    short8 a[4], b[4];
#pragma unroll
    for (int mt = 0; mt < 4; mt++)
      a[mt] = *(const short8*)(As + ((wm*64 + mt*16 + rb) * 32) + q*8);
#pragma unroll
    for (int nt = 0; nt < 4; nt++)
      b[nt] = *(const short8*)(Bs + ((wn*64 + nt*16 + rb) * 32) + q*8);
#pragma unroll
    for (int mt = 0; mt < 4; mt++)
#pragma unroll
      for (int nt = 0; nt < 4; nt++)
        acc[mt][nt] = __builtin_amdgcn_mfma_f32_16x16x32_bf16(a[mt], b[nt], acc[mt][nt], 0, 0, 0);
  }

  // LoRA B factors for this lane's 4 columns
  float b0c[4], b1c[4];
#pragma unroll
  for (int nt = 0; nt < 4; nt++){
    int col = col0 + wn*64 + rb + nt*16;
    b0c[nt] = Bl[(e*2+0)*N + col];
    b1c[nt] = Bl[(e*2+1)*N + col];
  }

#pragma unroll
  for (int mt = 0; mt < 4; mt++){
#pragma unroll
    for (int r = 0; r < 4; r++){
      int row = row0 + wm*64 + mt*16 + q*4 + r;
      float2 u = *(const float2*)(U + row*2);
      float wv = 0.f; int tb = 0;
      if (COMBINE){ wv = wslot[row]; tb = tbat[row]; }
      size_t base = (size_t)row * N + col0 + wn*64 + rb;
#pragma unroll
      for (int nt = 0; nt < 4; nt++){
        float v = acc[mt][nt][r] + LSCALE*(u.x*b0c[nt] + u.y*b1c[nt]);
        if (GELU) v = gelu_tanh(v);
        if (COMBINE){
          if (wv != 0.f) atomicAdd(&part[tb*128 + wn*64 + rb + nt*16], wv*v);
        } else {
          Cb[base + nt*16] = f2bf(v);
        }
      }
    }
  }

  if (COMBINE){
    __syncthreads();
#pragma unroll
    for (int idx = tid; idx < 512; idx += 256){
      float pv = part[idx];
      if (pv != 0.f) atomicAdd(pooled + (size_t)(idx >> 7) * D_MODEL + col0 + (idx & 127), pv);
    }
  }
}

// ---------------- head: out[b][c] = mean_pool . Wh + bh ----------------------
__global__ void head_kernel(const float* __restrict__ pooled, const float* __restrict__ Wh,
                            const float* __restrict__ bh, float* __restrict__ out)
{
  int lane = threadIdx.x & 63;
  int wave = threadIdx.x >> 6;            // 8 waves: (b, c)
  int b = wave >> 1, c = wave & 1;
  float s = 0.f;
#pragma unroll
  for (int i = 0; i < 16; i++){
    int d = lane + i*64;
    s += pooled[(size_t)b * D_MODEL + d] * Wh[d*2 + c];
  }
#pragma unroll
  for (int off = 32; off > 0; off >>= 1) s += __shfl_down(s, off);
  if (lane == 0) out[b*2 + c] = s * (1.0f/2048.0f) + bh[c];
}

// ---------------- launch ------------------------------------------------------
extern "C" void kernel_launch(void* const* d_in, const int* in_sizes, int n_in,
                              void* d_out, int out_size, void* d_ws, size_t ws_size,
                              hipStream_t stream)
{
  const float* x  = (const float*)d_in[0];
  const float* Wg = (const float*)d_in[1];
  const float* W1 = (const float*)d_in[2];
  const float* W2 = (const float*)d_in[3];
  const float* A1 = (const float*)d_in[4];
  const float* B1 = (const float*)d_in[5];
  const float* A2 = (const float*)d_in[6];
  const float* B2 = (const float*)d_in[7];
  const float* Wh = (const float*)d_in[8];
  const float* bh = (const float*)d_in[9];
  float* out = (float*)d_out;

  char* p = (char*)d_ws;
  auto alloc = [&](size_t bytes){
    char* r = p;
    p += (bytes + 255) & ~(size_t)255;
    return (void*)r;
  };
  unsigned short* W1bf  = (unsigned short*)alloc((size_t)FF_DIM*D_MODEL*2);       // 8 MB
  unsigned short* W2bf  = (unsigned short*)alloc((size_t)D_MODEL*FF_DIM*2);       // 8 MB
  unsigned short* dispA = (unsigned short*)alloc((size_t)ECAP*D_MODEL*2);         // 40 MB
  unsigned short* H     = (unsigned short*)alloc((size_t)ECAP*FF_DIM*2);          // 160 MB
  float* U1       = (float*)alloc((size_t)ECAP*2*4);
  float* U2       = (float*)alloc((size_t)ECAP*2*4);
  float* wslot    = (float*)alloc((size_t)ECAP*4);
  int*   tbat     = (int*)  alloc((size_t)ECAP*4);
  int*   exp_flat = (int*)  alloc((size_t)2*TOK*4);
  float* g_flat   = (float*)alloc((size_t)2*TOK*4);
  int*   slotidx  = (int*)  alloc((size_t)2*TOK*4);
  float* wcomb    = (float*)alloc((size_t)2*TOK*4);
  int*   fillc    = (int*)  alloc(256);
  float* pooled   = (float*)alloc((size_t)4*D_MODEL*4);

  tr_w1<<<dim3(16,64), 256, 0, stream>>>(W1, W1bf);
  tr_w2<<<dim3(16,64), 256, 0, stream>>>(W2, W2bf);
  gate_kernel<<<2048, 256, 0, stream>>>(x, Wg, exp_flat, g_flat);
  route_kernel<<<1, 64, 0, stream>>>(exp_flat, g_flat, slotidx, wcomb, fillc);
  init_zero<<<96, 256, 0, stream>>>(pooled, wslot);
  dispatch_kernel<<<2*TOK, 128, 0, stream>>>(x, slotidx, wcomb, dispA, wslot, tbat);
  lora_u<<<5120, 256, 0, stream>>>(dispA, A1, U1, D_MODEL);
  gemm_bt<true, false><<<dim3(160,32), 256, 0, stream>>>(dispA, W1bf, H, D_MODEL, FF_DIM,
                                                         fillc, U1, B1, nullptr, nullptr, nullptr);
  lora_u<<<5120, 256, 0, stream>>>(H, A2, U2, FF_DIM);
  gemm_bt<false, true><<<dim3(160, 8), 256, 0, stream>>>(H, W2bf, nullptr, FF_DIM, D_MODEL,
                                                         fillc, U2, B2, wslot, tbat, pooled);
  head_kernel<<<1, 512, 0, stream>>>(pooled, Wh, bh, out);
}

// Round 3
// 697.059 us; speedup vs baseline: 1.2807x; 1.2807x over previous
//
#include <hip/hip_runtime.h>
#include <hip/hip_bf16.h>
#include <cstdint>
#include <cstddef>

#define D_MODEL 1024
#define FF_DIM  4096
#define NEXP    8
#define TOK     8192
#define CAP     2560          // ceil(1.25 * 8192*2 / 8)
#define ECAP    (NEXP*CAP)    // 20480
#define LSCALE  2.0f          // lora_alpha / rank = 4/2
#define SA_BYTE 124           // activations stored x8  -> scale 2^-3
#define SB_BYTE 122           // weights stored x32     -> scale 2^-5

typedef __attribute__((ext_vector_type(8))) int   int32x8;
typedef __attribute__((ext_vector_type(4))) float f32x4;
typedef __attribute__((ext_vector_type(2))) float f32x2;

__device__ __forceinline__ void gload16(const void* g, void* l){
  __builtin_amdgcn_global_load_lds((const __attribute__((address_space(1))) void*)g,
                                   (__attribute__((address_space(3))) void*)l, 16, 0, 0);
}
__device__ __forceinline__ float gelu_tanh(float x){
  float u = 0.7978845608028654f * (x + 0.044715f * x * x * x);
  float e = __expf(2.0f * u);
  float t = 1.0f - 2.0f / (e + 1.0f);
  return 0.5f * x * (1.0f + t);
}

// ------- quantize+transpose W1 [D][FF] -> W1q [FF][D] fp8 e4m3, x32 ----------
__global__ void qt_w1(const float* __restrict__ W1, uint8_t* __restrict__ W1q)
{
  __shared__ float tile[64][65];          // tile[d_local][f_local]
  int d0 = blockIdx.x * 64;               // 16 blocks
  int f0 = blockIdx.y * 64;               // 64 blocks
  int tid = threadIdx.x;
  int r  = tid >> 4;                      // 0..15
  int c4 = (tid & 15) * 4;                // 0..60
#pragma unroll
  for (int i = 0; i < 4; i++){
    int dl = r + i*16;
    float4 v = *(const float4*)(W1 + (size_t)(d0 + dl) * FF_DIM + f0 + c4);
    tile[dl][c4+0] = v.x; tile[dl][c4+1] = v.y; tile[dl][c4+2] = v.z; tile[dl][c4+3] = v.w;
  }
  __syncthreads();
#pragma unroll
  for (int i = 0; i < 4; i++){
    int fl = r + i*16;
    int f  = f0 + fl;
    int pk = __builtin_amdgcn_cvt_pk_fp8_f32(32.f*tile[c4+0][fl], 32.f*tile[c4+1][fl], 0, false);
    pk     = __builtin_amdgcn_cvt_pk_fp8_f32(32.f*tile[c4+2][fl], 32.f*tile[c4+3][fl], pk, true);
    *(int*)(W1q + (size_t)f * D_MODEL + d0 + c4) = pk;
  }
}

// ------- quantize+transpose W2 [FF][D] -> W2q [D][FF] fp8 e4m3, x32 ----------
__global__ void qt_w2(const float* __restrict__ W2, uint8_t* __restrict__ W2q)
{
  __shared__ float tile[64][65];          // tile[f_local][d_local]
  int d0 = blockIdx.x * 64;               // 16 blocks
  int f0 = blockIdx.y * 64;               // 64 blocks
  int tid = threadIdx.x;
  int r  = tid >> 4;
  int c4 = (tid & 15) * 4;
#pragma unroll
  for (int i = 0; i < 4; i++){
    int fl = r + i*16;
    float4 v = *(const float4*)(W2 + (size_t)(f0 + fl) * D_MODEL + d0 + c4);
    tile[fl][c4+0] = v.x; tile[fl][c4+1] = v.y; tile[fl][c4+2] = v.z; tile[fl][c4+3] = v.w;
  }
  __syncthreads();
#pragma unroll
  for (int i = 0; i < 4; i++){
    int dl = r + i*16;
    int d  = d0 + dl;
    int pk = __builtin_amdgcn_cvt_pk_fp8_f32(32.f*tile[c4+0][dl], 32.f*tile[c4+1][dl], 0, false);
    pk     = __builtin_amdgcn_cvt_pk_fp8_f32(32.f*tile[c4+2][dl], 32.f*tile[c4+3][dl], pk, true);
    *(int*)(W2q + (size_t)d * FF_DIM + f0 + c4) = pk;
  }
}

// ---------------- gating: one wave per token (exact f32, matches ref) --------
__global__ void gate_kernel(const float* __restrict__ x, const float* __restrict__ Wg,
                            int* __restrict__ exp_flat, float* __restrict__ g_flat)
{
  int lane = threadIdx.x & 63;
  int wave = threadIdx.x >> 6;
  int t = blockIdx.x * 4 + wave;
  const float4* xv = (const float4*)(x + (size_t)t * D_MODEL);
  float acc[8];
#pragma unroll
  for (int e = 0; e < 8; e++) acc[e] = 0.f;
#pragma unroll
  for (int i = 0; i < 4; i++){
    int i4 = lane + i*64;
    float4 v = xv[i4];
#pragma unroll
    for (int k = 0; k < 4; k++){
      float xs = (&v.x)[k];
      const float4* wr = (const float4*)(Wg + (size_t)(i4*4 + k) * 8);
      float4 w0 = wr[0], w1 = wr[1];
      acc[0] += xs*w0.x; acc[1] += xs*w0.y; acc[2] += xs*w0.z; acc[3] += xs*w0.w;
      acc[4] += xs*w1.x; acc[5] += xs*w1.y; acc[6] += xs*w1.z; acc[7] += xs*w1.w;
    }
  }
#pragma unroll
  for (int off = 32; off > 0; off >>= 1){
#pragma unroll
    for (int e = 0; e < 8; e++) acc[e] += __shfl_down(acc[e], off);
  }
  if (lane == 0){
    float m0 = acc[0]; int e0 = 0;
#pragma unroll
    for (int e = 1; e < 8; e++) if (acc[e] > m0){ m0 = acc[e]; e0 = e; }
    float m1 = -3.4e38f; int e1 = 0;
#pragma unroll
    for (int e = 0; e < 8; e++) if (e != e0 && acc[e] > m1){ m1 = acc[e]; e1 = e; }
    float z = __expf(m1 - m0);
    float inv = 1.f / (1.f + z);
    exp_flat[t]       = e0;
    exp_flat[TOK + t] = e1;
    g_flat[t]         = inv;
    g_flat[TOK + t]   = z * inv;
  }
}

// ---------------- routing: exact slot-major cumulative positions -------------
__global__ void route_kernel(const int* __restrict__ exp_flat, const float* __restrict__ g_flat,
                             int* __restrict__ slotidx, float* __restrict__ wcomb,
                             int* __restrict__ fillc)
{
  int lane = threadIdx.x;  // 64 threads, single wave
  unsigned long long ltmask = (1ull << lane) - 1ull;
  int cnt[8];
#pragma unroll
  for (int q = 0; q < 8; q++) cnt[q] = 0;
  int   e_cur = exp_flat[lane];
  float g_cur = g_flat[lane];
  for (int j0 = 0; j0 < 2*TOK; j0 += 64){
    int e_nxt = 0; float g_nxt = 0.f;
    if (j0 + 64 < 2*TOK){                 // prefetch next chunk (hide latency)
      e_nxt = exp_flat[j0 + 64 + lane];
      g_nxt = g_flat[j0 + 64 + lane];
    }
    int pos = 0;
#pragma unroll
    for (int q = 0; q < 8; q++){
      unsigned long long m = __ballot(e_cur == q);
      if (e_cur == q) pos = cnt[q] + __popcll(m & ltmask);
      cnt[q] += __popcll(m);
    }
    bool keep = pos < CAP;
    slotidx[j0 + lane] = e_cur*CAP + (keep ? pos : (CAP-1));
    wcomb[j0 + lane]   = keep ? g_cur : 0.f;
    e_cur = e_nxt; g_cur = g_nxt;
  }
  if (lane < 8) fillc[lane] = cnt[lane] < CAP ? cnt[lane] : CAP;
}

// ---------------- init: zero pooled + wslot ----------------------------------
__global__ void init_zero(float* __restrict__ pooled, float* __restrict__ wslot)
{
  int i = blockIdx.x * 256 + threadIdx.x;   // grid 96 -> 24576 = 4096 + 20480
  if (i < 4*D_MODEL) pooled[i] = 0.f;
  else wslot[i - 4*D_MODEL] = 0.f;
}

// ---------------- dispatch: scatter tokens -> fp8 capacity buffer (x8) -------
__global__ void dispatch_kernel(const float* __restrict__ x, const int* __restrict__ slotidx,
                                const float* __restrict__ wcomb, uint8_t* __restrict__ dispA,
                                float* __restrict__ wslot, int* __restrict__ tbat)
{
  int j = blockIdx.x;
  float w = wcomb[j];
  if (w == 0.f) return;                 // dropped (uniform branch)
  int t = j & (TOK - 1);
  int slot = slotidx[j];
  int i = threadIdx.x;                  // 128 threads, 8 elems each
  const float4* src = (const float4*)(x + (size_t)t * D_MODEL);
  float4 a = src[2*i], b = src[2*i+1];
  int p0 = __builtin_amdgcn_cvt_pk_fp8_f32(8.f*a.x, 8.f*a.y, 0, false);
  p0     = __builtin_amdgcn_cvt_pk_fp8_f32(8.f*a.z, 8.f*a.w, p0, true);
  int p1 = __builtin_amdgcn_cvt_pk_fp8_f32(8.f*b.x, 8.f*b.y, 0, false);
  p1     = __builtin_amdgcn_cvt_pk_fp8_f32(8.f*b.z, 8.f*b.w, p1, true);
  int2 o; o.x = p0; o.y = p1;
  *(int2*)(dispA + (size_t)slot * D_MODEL + i*8) = o;
  if (i == 0){ wslot[slot] = w; tbat[slot] = t >> 11; }
}

// ------- LoRA rank-2 projection: U[slot][r] = (X_row/8) . A_e[:,r] -----------
__global__ void lora_u(const uint8_t* __restrict__ X, const float* __restrict__ Aw,
                       float* __restrict__ U, int Kdim)
{
  int lane = threadIdx.x & 63;
  int wv   = threadIdx.x >> 6;
  int slot = blockIdx.x * 4 + wv;       // 5120 blocks -> 20480 slots
  int e = slot / CAP;
  const int4*   row = (const int4*)(X + (size_t)slot * Kdim);   // 16 elems / int4
  const float2* Av  = (const float2*)(Aw + (size_t)e * Kdim * 2);
  float a0 = 0.f, a1 = 0.f;
  int n16 = Kdim >> 4;
  for (int i = lane; i < n16; i += 64){
    int4 v = row[i];
    int d = i * 16;
#pragma unroll
    for (int c = 0; c < 4; c++){
      int w = (&v.x)[c];
      f32x2 f01 = __builtin_amdgcn_cvt_pk_f32_fp8(w, false);
      f32x2 f23 = __builtin_amdgcn_cvt_pk_f32_fp8(w, true);
      int dd = d + c*4;
      float2 w0 = Av[dd], w1 = Av[dd+1], w2 = Av[dd+2], w3 = Av[dd+3];
      a0 += f01.x*w0.x + f01.y*w1.x + f23.x*w2.x + f23.y*w3.x;
      a1 += f01.x*w0.y + f01.y*w1.y + f23.x*w2.y + f23.y*w3.y;
    }
  }
#pragma unroll
  for (int off = 32; off > 0; off >>= 1){
    a0 += __shfl_down(a0, off);
    a1 += __shfl_down(a1, off);
  }
  if (lane == 0){ U[slot*2] = a0 * 0.125f; U[slot*2+1] = a1 * 0.125f; }
}

// ---------------- MX-fp8 GEMM, C = (A/8) * (Bt/32)^T + LoRA ------------------
// A [20480][K] fp8 bytes (x8), Bt [N][K] fp8 (x32, shared), XOR-swizzled LDS.
// GELU: apply gelu, write fp8 (x8).  COMBINE: pooled += w*val.
template<bool GELU, bool COMBINE>
__global__ __launch_bounds__(256) void gemm_mx(const uint8_t* __restrict__ A,
                                               const uint8_t* __restrict__ Bt,
                                               uint8_t* __restrict__ Cb,
                                               int K, int N, const int* __restrict__ fillc,
                                               const float* __restrict__ U,
                                               const float* __restrict__ Bl,
                                               const float* __restrict__ wslot,
                                               const int* __restrict__ tbat,
                                               float* __restrict__ pooled)
{
  int e = blockIdx.x / 20;                       // CAP/128 = 20 row tiles per expert
  if ((blockIdx.x % 20) * 128 >= fillc[e]) return;
  int row0 = blockIdx.x * 128;
  int col0 = blockIdx.y * 128;

  __shared__ __align__(16) uint8_t As[128*128];  // 16 KB, rows 128B (= 32 banks)
  __shared__ __align__(16) uint8_t Bs[128*128];  // 16 KB
  __shared__ float part[512];                    // [4 batches][128 cols] for COMBINE

  int tid  = threadIdx.x;
  int lane = tid & 63;
  int wave = tid >> 6;
  int wm = wave & 1, wn = wave >> 1;

  if (COMBINE){ part[tid] = 0.f; part[tid + 256] = 0.f; }

  // staging: each gload covers 8 rows x 8 chunks(16B); source chunk XOR-swizzled
  int r8 = lane >> 3;                  // row within 8-row group
  int cs = (lane & 7) ^ r8;            // swizzled global chunk
  const uint8_t* gA = A  + (size_t)(row0 + wave*32 + r8) * K + cs*16;
  const uint8_t* gB = Bt + (size_t)(col0 + wave*32 + r8) * K + cs*16;
  uint8_t* lA = As + wave*32*128;      // wave-uniform LDS base
  uint8_t* lB = Bs + wave*32*128;

  f32x4 acc[4][4];
#pragma unroll
  for (int i = 0; i < 4; i++)
#pragma unroll
    for (int j = 0; j < 4; j++)
      acc[i][j] = (f32x4){0.f, 0.f, 0.f, 0.f};

  int rb = lane & 15;
  int q  = lane >> 4;                  // k-group: k = q*32..q*32+31

  for (int k0 = 0; k0 < K; k0 += 128){
    __syncthreads();
#pragma unroll
    for (int g = 0; g < 4; g++){
      gload16(gA + k0 + (size_t)g*8*K, lA + g*1024);
      gload16(gB + k0 + (size_t)g*8*K, lB + g*1024);
    }
    __syncthreads();
    int32x8 a[4], b[4];
#pragma unroll
    for (int mt = 0; mt < 4; mt++){
      int row = wm*64 + mt*16 + rb;
      const uint8_t* base = As + row*128;
      int sw = row & 7;
      int4 lo = *(const int4*)(base + (((2*q)  ^sw)*16));
      int4 hi = *(const int4*)(base + (((2*q+1)^sw)*16));
      int32x8 v; v[0]=lo.x; v[1]=lo.y; v[2]=lo.z; v[3]=lo.w;
                 v[4]=hi.x; v[5]=hi.y; v[6]=hi.z; v[7]=hi.w;
      a[mt] = v;
    }
#pragma unroll
    for (int nt = 0; nt < 4; nt++){
      int row = wn*64 + nt*16 + rb;
      const uint8_t* base = Bs + row*128;
      int sw = row & 7;
      int4 lo = *(const int4*)(base + (((2*q)  ^sw)*16));
      int4 hi = *(const int4*)(base + (((2*q+1)^sw)*16));
      int32x8 v; v[0]=lo.x; v[1]=lo.y; v[2]=lo.z; v[3]=lo.w;
                 v[4]=hi.x; v[5]=hi.y; v[6]=hi.z; v[7]=hi.w;
      b[nt] = v;
    }
#pragma unroll
    for (int mt = 0; mt < 4; mt++)
#pragma unroll
      for (int nt = 0; nt < 4; nt++)
        acc[mt][nt] = __builtin_amdgcn_mfma_scale_f32_16x16x128_f8f6f4(
            a[mt], b[nt], acc[mt][nt], 0, 0, 0, SA_BYTE, 0, SB_BYTE);
  }

  // LoRA B factors for this lane's 4 columns
  float b0c[4], b1c[4];
#pragma unroll
  for (int nt = 0; nt < 4; nt++){
    int col = col0 + wn*64 + rb + nt*16;
    b0c[nt] = Bl[(e*2+0)*N + col];
    b1c[nt] = Bl[(e*2+1)*N + col];
  }

#pragma unroll
  for (int mt = 0; mt < 4; mt++){
#pragma unroll
    for (int r = 0; r < 4; r++){
      int row = row0 + wm*64 + mt*16 + q*4 + r;
      float2 u = *(const float2*)(U + row*2);
      float wv = 0.f; int tb = 0;
      if (COMBINE){ wv = wslot[row]; tb = tbat[row]; }
      size_t base = (size_t)row * N + col0 + wn*64 + rb;
#pragma unroll
      for (int nt = 0; nt < 4; nt++){
        float v = acc[mt][nt][r] + LSCALE*(u.x*b0c[nt] + u.y*b1c[nt]);
        if (GELU){
          v = gelu_tanh(v);
          int pk = __builtin_amdgcn_cvt_pk_fp8_f32(8.f*v, 0.f, 0, false);
          Cb[base + nt*16] = (uint8_t)(pk & 0xFF);
        }
        if (COMBINE){
          if (wv != 0.f) atomicAdd(&part[tb*128 + wn*64 + rb + nt*16], wv*v);
        }
      }
    }
  }

  if (COMBINE){
    __syncthreads();
#pragma unroll
    for (int idx = tid; idx < 512; idx += 256){
      float pv = part[idx];
      if (pv != 0.f) atomicAdd(pooled + (size_t)(idx >> 7) * D_MODEL + col0 + (idx & 127), pv);
    }
  }
}

// ---------------- head: out[b][c] = mean_pool . Wh + bh ----------------------
__global__ void head_kernel(const float* __restrict__ pooled, const float* __restrict__ Wh,
                            const float* __restrict__ bh, float* __restrict__ out)
{
  int lane = threadIdx.x & 63;
  int wave = threadIdx.x >> 6;            // 8 waves: (b, c)
  int b = wave >> 1, c = wave & 1;
  float s = 0.f;
#pragma unroll
  for (int i = 0; i < 16; i++){
    int d = lane + i*64;
    s += pooled[(size_t)b * D_MODEL + d] * Wh[d*2 + c];
  }
#pragma unroll
  for (int off = 32; off > 0; off >>= 1) s += __shfl_down(s, off);
  if (lane == 0) out[b*2 + c] = s * (1.0f/2048.0f) + bh[c];
}

// ---------------- launch ------------------------------------------------------
extern "C" void kernel_launch(void* const* d_in, const int* in_sizes, int n_in,
                              void* d_out, int out_size, void* d_ws, size_t ws_size,
                              hipStream_t stream)
{
  const float* x  = (const float*)d_in[0];
  const float* Wg = (const float*)d_in[1];
  const float* W1 = (const float*)d_in[2];
  const float* W2 = (const float*)d_in[3];
  const float* A1 = (const float*)d_in[4];
  const float* B1 = (const float*)d_in[5];
  const float* A2 = (const float*)d_in[6];
  const float* B2 = (const float*)d_in[7];
  const float* Wh = (const float*)d_in[8];
  const float* bh = (const float*)d_in[9];
  float* out = (float*)d_out;

  char* p = (char*)d_ws;
  auto alloc = [&](size_t bytes){
    char* r = p;
    p += (bytes + 255) & ~(size_t)255;
    return (void*)r;
  };
  uint8_t* W1q   = (uint8_t*)alloc((size_t)FF_DIM*D_MODEL);     // 4 MB
  uint8_t* W2q   = (uint8_t*)alloc((size_t)D_MODEL*FF_DIM);     // 4 MB
  uint8_t* dispA = (uint8_t*)alloc((size_t)ECAP*D_MODEL);       // 20 MB
  uint8_t* H     = (uint8_t*)alloc((size_t)ECAP*FF_DIM);        // 80 MB
  float* U1       = (float*)alloc((size_t)ECAP*2*4);
  float* U2       = (float*)alloc((size_t)ECAP*2*4);
  float* wslot    = (float*)alloc((size_t)ECAP*4);
  int*   tbat     = (int*)  alloc((size_t)ECAP*4);
  int*   exp_flat = (int*)  alloc((size_t)2*TOK*4);
  float* g_flat   = (float*)alloc((size_t)2*TOK*4);
  int*   slotidx  = (int*)  alloc((size_t)2*TOK*4);
  float* wcomb    = (float*)alloc((size_t)2*TOK*4);
  int*   fillc    = (int*)  alloc(256);
  float* pooled   = (float*)alloc((size_t)4*D_MODEL*4);

  qt_w1<<<dim3(16,64), 256, 0, stream>>>(W1, W1q);
  qt_w2<<<dim3(16,64), 256, 0, stream>>>(W2, W2q);
  gate_kernel<<<2048, 256, 0, stream>>>(x, Wg, exp_flat, g_flat);
  route_kernel<<<1, 64, 0, stream>>>(exp_flat, g_flat, slotidx, wcomb, fillc);
  init_zero<<<96, 256, 0, stream>>>(pooled, wslot);
  dispatch_kernel<<<2*TOK, 128, 0, stream>>>(x, slotidx, wcomb, dispA, wslot, tbat);
  lora_u<<<5120, 256, 0, stream>>>(dispA, A1, U1, D_MODEL);
  gemm_mx<true, false><<<dim3(160,32), 256, 0, stream>>>(dispA, W1q, H, D_MODEL, FF_DIM,
                                                         fillc, U1, B1, nullptr, nullptr, nullptr);
  lora_u<<<5120, 256, 0, stream>>>(H, A2, U2, FF_DIM);
  gemm_mx<false, true><<<dim3(160, 8), 256, 0, stream>>>(H, W2q, nullptr, FF_DIM, D_MODEL,
                                                         fillc, U2, B2, wslot, tbat, pooled);
  head_kernel<<<1, 512, 0, stream>>>(pooled, Wh, bh, out);
}